// Round 4
// baseline (551.482 us; speedup 1.0000x reference)
//
#include <hip/hip_runtime.h>
#include <hip/hip_bf16.h>

#define GPTR(p) ((__attribute__((address_space(1))) void*)(p))
#define LPTR(p) ((__attribute__((address_space(3))) void*)(p))

typedef __attribute__((ext_vector_type(8))) short short8;
typedef __attribute__((ext_vector_type(4))) float f32x4;
typedef __attribute__((ext_vector_type(16))) float f32x16;
typedef unsigned short u16t;
typedef unsigned int u32t;

#define NHEAD 16
#define DK 64
#define NF 1024
#define BB 4
#define TT 2048
#define BT (BB * TT) /* 8192 */

static __device__ __forceinline__ u16t f2bf(float f) {
  union { float f; unsigned u; } c; c.f = f;
  unsigned r = c.u + 0x7fffu + ((c.u >> 16) & 1u);
  return (u16t)(r >> 16);
}

__global__ void cvt_kernel(const float* __restrict__ src, u16t* __restrict__ dst, int n4) {
  int stride = gridDim.x * blockDim.x;
  for (int i = blockIdx.x * blockDim.x + threadIdx.x; i < n4; i += stride) {
    float4 f = reinterpret_cast<const float4*>(src)[i];
    ushort4 o;
    o.x = f2bf(f.x); o.y = f2bf(f.y); o.z = f2bf(f.z); o.w = f2bf(f.w);
    reinterpret_cast<ushort4*>(dst)[i] = o;
  }
}

// C = (A @ W^T + bias) * 0.125 * log2(e) ; bf16 out, fp32 acc
__launch_bounds__(256, 2)
__global__ void qproj_kernel(const u16t* __restrict__ A, const u16t* __restrict__ W,
                             const float* __restrict__ bias, u16t* __restrict__ C) {
  __shared__ u16t As[128 * 64];
  __shared__ u16t Bs[128 * 64];
  const int tid = threadIdx.x;
  const int m0 = blockIdx.x * 128;
  const int n0 = blockIdx.y * 128;
  const int w = tid >> 6, lane = tid & 63;
  const int wr = (w >> 1) * 64, wc = (w & 1) * 64;
  const int g = lane >> 4, r = lane & 15;

  f32x4 acc[4][4] = {};

  for (int kb = 0; kb < NF; kb += 64) {
    __syncthreads();
#pragma unroll
    for (int i = 0; i < 4; ++i) {
      int c = i * 256 + tid;
      int row = c >> 3, slot = c & 7;
      int gs = slot ^ (row & 7);
      __builtin_amdgcn_global_load_lds(GPTR(A + (size_t)(m0 + row) * NF + kb + gs * 8),
                                       LPTR(As + c * 8), 16, 0, 0);
    }
#pragma unroll
    for (int i = 0; i < 4; ++i) {
      int c = i * 256 + tid;
      int row = c >> 3, slot = c & 7;
      int gs = slot ^ (row & 7);
      __builtin_amdgcn_global_load_lds(GPTR(W + (size_t)(n0 + row) * NF + kb + gs * 8),
                                       LPTR(Bs + c * 8), 16, 0, 0);
    }
    __syncthreads();
#pragma unroll
    for (int kk = 0; kk < 2; ++kk) {
      short8 af[4], bfr[4];
#pragma unroll
      for (int i = 0; i < 4; ++i) {
        int row = wr + i * 16 + r;
        int slot = (4 * kk + g) ^ (row & 7);
        af[i] = *reinterpret_cast<const short8*>(As + row * 64 + slot * 8);
      }
#pragma unroll
      for (int j = 0; j < 4; ++j) {
        int row = wc + j * 16 + r;
        int slot = (4 * kk + g) ^ (row & 7);
        bfr[j] = *reinterpret_cast<const short8*>(Bs + row * 64 + slot * 8);
      }
#pragma unroll
      for (int i = 0; i < 4; ++i)
#pragma unroll
        for (int j = 0; j < 4; ++j)
          acc[i][j] = __builtin_amdgcn_mfma_f32_16x16x32_bf16(af[i], bfr[j], acc[i][j], 0, 0, 0);
    }
  }
#pragma unroll
  for (int i = 0; i < 4; ++i)
#pragma unroll
    for (int j = 0; j < 4; ++j) {
      int grow = m0 + wr + i * 16 + 4 * g;
      int gcol = n0 + wc + j * 16 + r;
      float bv = bias[gcol];
#pragma unroll
      for (int reg = 0; reg < 4; ++reg)
        C[(size_t)(grow + reg) * NF + gcol] = f2bf((acc[i][j][reg] + bv) * 0.18033688f);
    }
}

// Flash attention, swapped-QK^T: 8 waves x 32 q-rows, KVBLK=64, 32x32x16 MFMA.
// Double-buffered K/V LDS, 1 barrier/tile (T14). exp2-based softmax, no max-sub.
// LDS map (32KB): K0 @0, K1 @8192, V0 @16384, V1 @24576.
//  K rows 128B, 16B-slot s holds d-granule (s ^ (kv&7))  [DMA pre-swizzled source]
//  V b64 granule (Q=kv>>2, d) at byte d*128 + ((Q ^ (d&15) ^ ((d>>4)&3))<<3)
__launch_bounds__(512, 4)
__global__ void attn_kernel(const u16t* __restrict__ Q, const u16t* __restrict__ K,
                            const u16t* __restrict__ V, const int* __restrict__ mask,
                            float* __restrict__ O) {
  __shared__ __attribute__((aligned(16))) char lds[32768];

  const int tid = threadIdx.x;
  const int lane = tid & 63;
  const int w = tid >> 6;
  const int qc = lane & 31;
  const int hi = lane >> 5;
  const int b = blockIdx.x >> 4, h = blockIdx.x & 15;
  const size_t bbase = (size_t)b * TT * NF;
  const int hoff = h * DK;
  const int qrow0 = blockIdx.y * 256 + w * 32;

  // Q B-frags held whole kernel
  short8 qa[4];
#pragma unroll
  for (int t = 0; t < 4; ++t)
    qa[t] = *reinterpret_cast<const short8*>(
        Q + bbase + (size_t)(qrow0 + qc) * NF + hoff + 16 * t + 8 * hi);

  f32x16 oacc[2] = {};
  float lsum = 0.f;

  // K staging (DMA): chunk = tid, row = tid>>3, slot = tid&7, pre-swizzled source
  const int srow = tid >> 3, sslot = tid & 7;
  const u16t* Ksrc = K + bbase + (size_t)srow * NF + hoff + ((sslot ^ (srow & 7)) * 8);

  // V staging: thread = (Qv = tid>>5, sub = (tid>>4)&1, dq = tid&15)
  const int Qv = tid >> 5, sub = (tid >> 4) & 1, dq = tid & 15;
  const u16t* Vsrc = V + bbase + (size_t)(4 * Qv + 2 * sub) * NF + hoff + 4 * dq;
  const int slotbase = Qv ^ (dq >> 2) ^ (4 * (dq & 3));
  const int wbase = 16384 + 4 * dq * 128 + (slotbase << 3) + 4 * sub;

  const int* msrc = mask + b * TT + lane;

  // read-address bases
  const int kb0 = qc * 128 + ((hi ^ (qc & 7)) << 4);                      // K row qc
  const int g0 = hi ^ (qc & 15) ^ ((qc >> 4) & 3);
  const int g1 = hi ^ (qc & 15) ^ (((qc >> 4) + 2) & 3);
  const int vb0 = 16384 + qc * 128 + (g0 << 3);                          // V d=qc
  const int vb1 = 16384 + (qc + 32) * 128 + (g1 << 3);                   // V d=qc+32

  // prologue: stage tile 0
  uint2 va = *reinterpret_cast<const uint2*>(Vsrc);
  uint2 vbl = *reinterpret_cast<const uint2*>(Vsrc + NF);
  int mv = msrc[0];
  __builtin_amdgcn_global_load_lds(GPTR(Ksrc), LPTR(lds + tid * 16), 16, 0, 0);
  Ksrc += (size_t)64 * NF;
  Vsrc += (size_t)64 * NF;

#define ATTN_BODY(T2, CB)                                                              \
  {                                                                                    \
    const int nt2 = (T2) + 64;                                                         \
    { /* A: write V(t) into V[CB] */                                                   \
      u32t pk0 = (va.x & 0xffffu) | (vbl.x << 16);                                     \
      u32t pk1 = (va.x >> 16) | (vbl.x & 0xffff0000u);                                 \
      u32t pk2 = (va.y & 0xffffu) | (vbl.y << 16);                                     \
      u32t pk3 = (va.y >> 16) | (vbl.y & 0xffff0000u);                                 \
      *reinterpret_cast<u32t*>(lds + (CB) + ((wbase) ^ (0 << 3)) + 0 * 128) = pk0;     \
      *reinterpret_cast<u32t*>(lds + (CB) + ((wbase) ^ (1 << 3)) + 1 * 128) = pk1;     \
      *reinterpret_cast<u32t*>(lds + (CB) + ((wbase) ^ (2 << 3)) + 2 * 128) = pk2;     \
      *reinterpret_cast<u32t*>(lds + (CB) + ((wbase) ^ (3 << 3)) + 3 * 128) = pk3;     \
    }                                                                                  \
    __syncthreads();                                                                   \
    unsigned long long bm = __ballot(mv != 0);                                         \
    if (nt2 < TT) { /* C: issue next-tile staging */                                   \
      __builtin_amdgcn_global_load_lds(GPTR(Ksrc), LPTR(lds + ((CB) ^ 8192) + tid * 16), 16, 0, 0); \
      Ksrc += (size_t)64 * NF;                                                         \
      va = *reinterpret_cast<const uint2*>(Vsrc);                                      \
      vbl = *reinterpret_cast<const uint2*>(Vsrc + NF);                                \
      Vsrc += (size_t)64 * NF;                                                         \
      mv = msrc[nt2];                                                                  \
    }                                                                                  \
    /* D: QK^T */                                                                      \
    f32x16 s0 = {}, s1 = {};                                                           \
    __builtin_amdgcn_s_setprio(1);                                                     \
    _Pragma("unroll")                                                                  \
    for (int t = 0; t < 4; ++t) {                                                      \
      short8 kf0 = *reinterpret_cast<const short8*>(lds + (((CB) + kb0) ^ (t << 5)));  \
      s0 = __builtin_amdgcn_mfma_f32_32x32x16_bf16(kf0, qa[t], s0, 0, 0, 0);           \
      short8 kf1 = *reinterpret_cast<const short8*>(lds + ((((CB) + kb0) ^ (t << 5)) + 4096)); \
      s1 = __builtin_amdgcn_mfma_f32_32x32x16_bf16(kf1, qa[t], s1, 0, 0, 0);           \
    }                                                                                  \
    __builtin_amdgcn_s_setprio(0);                                                     \
    /* softmax + pack + PV, per kv-16-slice t */                                       \
    _Pragma("unroll")                                                                  \
    for (int t = 0; t < 4; ++t) {                                                      \
      union { u32t u[4]; short8 s; } pa;                                               \
      _Pragma("unroll")                                                                \
      for (int i = 0; i < 4; ++i) {                                                    \
        const int reg = (t & 1) * 8 + 2 * i;                                           \
        const int kva = (reg & 3) + 8 * (reg >> 2) + 4 * hi + 32 * (t >> 1);           \
        float xa = ((bm >> kva) & 1ull) ? (t < 2 ? s0[reg] : s1[reg]) : -100.f;        \
        float xb = ((bm >> (kva + 1)) & 1ull) ? (t < 2 ? s0[reg + 1] : s1[reg + 1]) : -100.f; \
        xa = __builtin_exp2f(xa);                                                      \
        xb = __builtin_exp2f(xb);                                                      \
        lsum += xa + xb;                                                               \
        float2 ff; ff.x = xa; ff.y = xb;                                               \
        __hip_bfloat162 h2 = __float22bfloat162_rn(ff);                                \
        u32t uu; __builtin_memcpy(&uu, &h2, 4);                                        \
        pa.u[i] = uu;                                                                  \
      }                                                                                \
      {                                                                                \
        union { uint2 u2[2]; short8 s; } vf0, vf1;                                     \
        vf0.u2[0] = *reinterpret_cast<const uint2*>(lds + (((CB) + vb0) ^ ((4 * t) << 3)));     \
        vf0.u2[1] = *reinterpret_cast<const uint2*>(lds + (((CB) + vb0) ^ (((4 * t) ^ 2) << 3))); \
        vf1.u2[0] = *reinterpret_cast<const uint2*>(lds + (((CB) + vb1) ^ ((4 * t) << 3)));     \
        vf1.u2[1] = *reinterpret_cast<const uint2*>(lds + (((CB) + vb1) ^ (((4 * t) ^ 2) << 3))); \
        oacc[0] = __builtin_amdgcn_mfma_f32_32x32x16_bf16(pa.s, vf0.s, oacc[0], 0, 0, 0); \
        oacc[1] = __builtin_amdgcn_mfma_f32_32x32x16_bf16(pa.s, vf1.s, oacc[1], 0, 0, 0); \
      }                                                                                \
    }                                                                                  \
  }

  for (int t2 = 0; t2 < TT; t2 += 128) {
    ATTN_BODY(t2, 0)
    ATTN_BODY(t2 + 64, 8192)
  }
#undef ATTN_BODY

  // O[q][d]: C-layout row = (reg&3)+8*(reg>>2)+4hi, col = qc (+32)
  float lall = lsum + __shfl_xor(lsum, 32, 64);
  float linv = 1.0f / lall;
#pragma unroll
  for (int reg = 0; reg < 16; ++reg) {
    const int crow = (reg & 3) + 8 * (reg >> 2) + 4 * hi;
    float rl = __shfl(linv, crow, 64);
    float* orow = O + bbase + (size_t)(qrow0 + crow) * NF + hoff + qc;
    orow[0] = oacc[0][reg] * rl;
    orow[32] = oacc[1][reg] * rl;
  }
}

extern "C" void kernel_launch(void* const* d_in, const int* in_sizes, int n_in,
                              void* d_out, int out_size, void* d_ws, size_t ws_size,
                              hipStream_t stream) {
  const float* query = (const float*)d_in[0];
  const float* key   = (const float*)d_in[1];
  const float* value = (const float*)d_in[2];
  const int*   mask  = (const int*)d_in[3];
  const float* Wq    = (const float*)d_in[4];
  const float* bq    = (const float*)d_in[5];
  float* out = (float*)d_out;

  u16t* ws = (u16t*)d_ws;
  u16t* qb = ws;
  u16t* kb = ws + (size_t)8 * 1024 * 1024;
  u16t* vb = ws + (size_t)16 * 1024 * 1024;
  u16t* wb = ws + (size_t)24 * 1024 * 1024;
  u16t* qp = ws + (size_t)25 * 1024 * 1024;

  cvt_kernel<<<2048, 256, 0, stream>>>(query, qb, (BT * NF) / 4);
  cvt_kernel<<<2048, 256, 0, stream>>>(key,   kb, (BT * NF) / 4);
  cvt_kernel<<<2048, 256, 0, stream>>>(value, vb, (BT * NF) / 4);
  cvt_kernel<<<1024, 256, 0, stream>>>(Wq,    wb, (NF * NF) / 4);

  qproj_kernel<<<dim3(BT / 128, NF / 128), 256, 0, stream>>>(qb, wb, bq, qp);
  // grid.x = (b,h): all 8 q-tiles of one (b,h) share an XCD (flat%8 = bh%8)
  attn_kernel<<<dim3(BB * NHEAD, TT / 256), 512, 0, stream>>>(qp, kb, vb, mask, out);
}

// Round 5
// 395.224 us; speedup vs baseline: 1.3954x; 1.3954x over previous
//
#include <hip/hip_runtime.h>
#include <hip/hip_bf16.h>

#define GPTR(p) ((__attribute__((address_space(1))) void*)(p))
#define LPTR(p) ((__attribute__((address_space(3))) void*)(p))

typedef __attribute__((ext_vector_type(8))) short short8;
typedef __attribute__((ext_vector_type(4))) float f32x4;
typedef __attribute__((ext_vector_type(16))) float f32x16;
typedef unsigned short u16t;
typedef unsigned int u32t;

#define NHEAD 16
#define DK 64
#define NF 1024
#define BB 4
#define TT 2048
#define BT (BB * TT) /* 8192 */

static __device__ __forceinline__ u16t f2bf(float f) {
  union { float f; unsigned u; } c; c.f = f;
  unsigned r = c.u + 0x7fffu + ((c.u >> 16) & 1u);
  return (u16t)(r >> 16);
}

__global__ void cvt_kernel(const float* __restrict__ src, u16t* __restrict__ dst, int n4) {
  int stride = gridDim.x * blockDim.x;
  for (int i = blockIdx.x * blockDim.x + threadIdx.x; i < n4; i += stride) {
    float4 f = reinterpret_cast<const float4*>(src)[i];
    ushort4 o;
    o.x = f2bf(f.x); o.y = f2bf(f.y); o.z = f2bf(f.z); o.w = f2bf(f.w);
    reinterpret_cast<ushort4*>(dst)[i] = o;
  }
}

// C = (A @ W^T + bias) * 0.125 * log2(e) ; bf16 out, fp32 acc
__launch_bounds__(256, 2)
__global__ void qproj_kernel(const u16t* __restrict__ A, const u16t* __restrict__ W,
                             const float* __restrict__ bias, u16t* __restrict__ C) {
  __shared__ u16t As[128 * 64];
  __shared__ u16t Bs[128 * 64];
  const int tid = threadIdx.x;
  const int m0 = blockIdx.x * 128;
  const int n0 = blockIdx.y * 128;
  const int w = tid >> 6, lane = tid & 63;
  const int wr = (w >> 1) * 64, wc = (w & 1) * 64;
  const int g = lane >> 4, r = lane & 15;

  f32x4 acc[4][4] = {};

  for (int kb = 0; kb < NF; kb += 64) {
    __syncthreads();
#pragma unroll
    for (int i = 0; i < 4; ++i) {
      int c = i * 256 + tid;
      int row = c >> 3, slot = c & 7;
      int gs = slot ^ (row & 7);
      __builtin_amdgcn_global_load_lds(GPTR(A + (size_t)(m0 + row) * NF + kb + gs * 8),
                                       LPTR(As + c * 8), 16, 0, 0);
    }
#pragma unroll
    for (int i = 0; i < 4; ++i) {
      int c = i * 256 + tid;
      int row = c >> 3, slot = c & 7;
      int gs = slot ^ (row & 7);
      __builtin_amdgcn_global_load_lds(GPTR(W + (size_t)(n0 + row) * NF + kb + gs * 8),
                                       LPTR(Bs + c * 8), 16, 0, 0);
    }
    __syncthreads();
#pragma unroll
    for (int kk = 0; kk < 2; ++kk) {
      short8 af[4], bfr[4];
#pragma unroll
      for (int i = 0; i < 4; ++i) {
        int row = wr + i * 16 + r;
        int slot = (4 * kk + g) ^ (row & 7);
        af[i] = *reinterpret_cast<const short8*>(As + row * 64 + slot * 8);
      }
#pragma unroll
      for (int j = 0; j < 4; ++j) {
        int row = wc + j * 16 + r;
        int slot = (4 * kk + g) ^ (row & 7);
        bfr[j] = *reinterpret_cast<const short8*>(Bs + row * 64 + slot * 8);
      }
#pragma unroll
      for (int i = 0; i < 4; ++i)
#pragma unroll
        for (int j = 0; j < 4; ++j)
          acc[i][j] = __builtin_amdgcn_mfma_f32_16x16x32_bf16(af[i], bfr[j], acc[i][j], 0, 0, 0);
    }
  }
#pragma unroll
  for (int i = 0; i < 4; ++i)
#pragma unroll
    for (int j = 0; j < 4; ++j) {
      int grow = m0 + wr + i * 16 + 4 * g;
      int gcol = n0 + wc + j * 16 + r;
      float bv = bias[gcol];
#pragma unroll
      for (int reg = 0; reg < 4; ++reg)
        C[(size_t)(grow + reg) * NF + gcol] = f2bf((acc[i][j][reg] + bv) * 0.18033688f);
    }
}

// Flash attention, swapped-QK^T: 8 waves x 32 q-rows, KVBLK=64, 32x32x16 MFMA.
// R3 skeleton (2 barriers/tile, single-buffer LDS, loads at loop top) +
// conflict-free b64-granule V layout + exp2 softmax + cvt_pk packing.
// LDS (16KB): Kl @0 (64 rows x 128B, 16B-slot s holds d-granule s^(kv&7)),
//             Vt @8192 (d rows x 128B, 8B-slot s holds kv-granule Q = s^(d&15)^((d>>4)&3))
__launch_bounds__(512, 4)
__global__ void attn_kernel(const u16t* __restrict__ Q, const u16t* __restrict__ K,
                            const u16t* __restrict__ V, const int* __restrict__ mask,
                            float* __restrict__ O) {
  __shared__ __attribute__((aligned(16))) char lds[16384];

  const int tid = threadIdx.x;
  const int lane = tid & 63;
  const int w = tid >> 6;
  const int qc = lane & 31;   // q-col for S^T / d-col for PV output
  const int hi = lane >> 5;
  const int b = blockIdx.x >> 4, h = blockIdx.x & 15;
  const size_t bbase = (size_t)b * TT * NF;
  const int hoff = h * DK;
  const int qrow0 = blockIdx.y * 256 + w * 32;

  // Q B-frags (col=q=lane&31, k(d)=16t+8hi+e) held whole kernel
  short8 qa[4];
#pragma unroll
  for (int t = 0; t < 4; ++t)
    qa[t] = *reinterpret_cast<const short8*>(
        Q + bbase + (size_t)(qrow0 + qc) * NF + hoff + 16 * t + 8 * hi);

  f32x16 oacc[2] = {};
  float lsum = 0.f;

  // K staging (DMA): chunk = tid, row = tid>>3, slot = tid&7, pre-swizzled source
  const int srow = tid >> 3, sslot = tid & 7;
  const u16t* Ksrc = K + bbase + (size_t)srow * NF + hoff + ((sslot ^ (srow & 7)) * 8);

  // V staging: thread = (Qv = tid>>5, sub = (tid>>4)&1, dq = tid&15)
  const int Qv = tid >> 5, sub = (tid >> 4) & 1, dq = tid & 15;
  const u16t* Vsrc = V + bbase + (size_t)(4 * Qv + 2 * sub) * NF + hoff + 4 * dq;
  const int slotbase = Qv ^ (dq >> 2) ^ (4 * (dq & 3));
  const int wbase = 8192 + 4 * dq * 128 + (slotbase << 3) + 4 * sub;

  const int* msrc = mask + b * TT + lane;

  // read-address bases
  const int g0 = hi ^ (qc & 15) ^ ((qc >> 4) & 3);
  const int g1 = hi ^ (qc & 15) ^ (((qc >> 4) + 2) & 3);
  const int vb0 = 8192 + qc * 128 + (g0 << 3);         // V col d=qc
  const int vb1 = 8192 + (qc + 32) * 128 + (g1 << 3);  // V col d=qc+32

  for (int t2 = 0; t2 < TT; t2 += 64) {
    // loads at loop top (R3 schedule)
    uint2 va = *reinterpret_cast<const uint2*>(Vsrc);
    uint2 vbl = *reinterpret_cast<const uint2*>(Vsrc + NF);
    int mv = msrc[t2];
    __syncthreads();  // readers of previous tile done
    __builtin_amdgcn_global_load_lds(GPTR(Ksrc), LPTR(lds + tid * 16), 16, 0, 0);
    Ksrc += (size_t)64 * NF;
    Vsrc += (size_t)64 * NF;
    { // V writes: b64 granule (Qv, d), word sub; 2-way banked (free)
      u32t pk0 = (va.x & 0xffffu) | (vbl.x << 16);
      u32t pk1 = (va.x >> 16) | (vbl.x & 0xffff0000u);
      u32t pk2 = (va.y & 0xffffu) | (vbl.y << 16);
      u32t pk3 = (va.y >> 16) | (vbl.y & 0xffff0000u);
      *reinterpret_cast<u32t*>(lds + (wbase ^ (0 << 3)) + 0 * 128) = pk0;
      *reinterpret_cast<u32t*>(lds + (wbase ^ (1 << 3)) + 1 * 128) = pk1;
      *reinterpret_cast<u32t*>(lds + (wbase ^ (2 << 3)) + 2 * 128) = pk2;
      *reinterpret_cast<u32t*>(lds + (wbase ^ (3 << 3)) + 3 * 128) = pk3;
    }
    unsigned long long bm = __ballot(mv != 0);
    __syncthreads();  // K (vmcnt) + V (lgkm) staged

    // S^T[kv][q] = K Q^T : A-frag row = kv = lane&31 (+32), k(d) = 16t+8hi+e
    f32x16 s0 = {}, s1 = {};
#pragma unroll
    for (int t = 0; t < 4; ++t) {
      const int sl = ((2 * t + hi) ^ (qc & 7)) * 16;
      short8 kf0 = *reinterpret_cast<const short8*>(lds + qc * 128 + sl);
      s0 = __builtin_amdgcn_mfma_f32_32x32x16_bf16(kf0, qa[t], s0, 0, 0, 0);
      short8 kf1 = *reinterpret_cast<const short8*>(lds + (qc + 32) * 128 + sl);
      s1 = __builtin_amdgcn_mfma_f32_32x32x16_bf16(kf1, qa[t], s1, 0, 0, 0);
    }

    // Fused mask+exp2+denominator+pack+PV, per kv-16-slice t.
    // s-reg -> kv: kv = (reg&3) + 8*(reg>>2) + 4*hi (+32 for s1).
    // A-frag k-map (e<4: kv=16t+4hi+e, e>=4: kv=16t+8+4hi+e-4) matches the
    // V b64 layout's B-frag k-map exactly (granules Q=4t^hi, 4t^hi^2).
#pragma unroll
    for (int t = 0; t < 4; ++t) {
      union { u32t u[4]; short8 s; } pa;
#pragma unroll
      for (int i = 0; i < 4; ++i) {
        const int reg = (t & 1) * 8 + 2 * i;
        const int kva = (reg & 3) + 8 * (reg >> 2) + 4 * hi + 32 * (t >> 1);
        float xa = ((bm >> kva) & 1ull) ? (t < 2 ? s0[reg] : s1[reg]) : -100.f;
        float xb = ((bm >> (kva + 1)) & 1ull) ? (t < 2 ? s0[reg + 1] : s1[reg + 1]) : -100.f;
        xa = __builtin_exp2f(xa);
        xb = __builtin_exp2f(xb);
        lsum += xa + xb;
        float2 ff; ff.x = xa; ff.y = xb;
        __hip_bfloat162 h2 = __float22bfloat162_rn(ff);
        u32t uu; __builtin_memcpy(&uu, &h2, 4);
        pa.u[i] = uu;
      }
      union { uint2 u2[2]; short8 s; } vf0, vf1;
      vf0.u2[0] = *reinterpret_cast<const uint2*>(lds + (vb0 ^ ((4 * t) << 3)));
      vf0.u2[1] = *reinterpret_cast<const uint2*>(lds + (vb0 ^ (((4 * t) ^ 2) << 3)));
      vf1.u2[0] = *reinterpret_cast<const uint2*>(lds + (vb1 ^ ((4 * t) << 3)));
      vf1.u2[1] = *reinterpret_cast<const uint2*>(lds + (vb1 ^ (((4 * t) ^ 2) << 3)));
      oacc[0] = __builtin_amdgcn_mfma_f32_32x32x16_bf16(pa.s, vf0.s, oacc[0], 0, 0, 0);
      oacc[1] = __builtin_amdgcn_mfma_f32_32x32x16_bf16(pa.s, vf1.s, oacc[1], 0, 0, 0);
    }
  }

  // O[q][d]: C-layout row = (reg&3)+8*(reg>>2)+4hi, col = qc (+32)
  float lall = lsum + __shfl_xor(lsum, 32, 64);
  float linv = 1.0f / lall;
#pragma unroll
  for (int reg = 0; reg < 16; ++reg) {
    const int crow = (reg & 3) + 8 * (reg >> 2) + 4 * hi;
    float rl = __shfl(linv, crow, 64);
    float* orow = O + bbase + (size_t)(qrow0 + crow) * NF + hoff + qc;
    orow[0] = oacc[0][reg] * rl;
    orow[32] = oacc[1][reg] * rl;
  }
}

extern "C" void kernel_launch(void* const* d_in, const int* in_sizes, int n_in,
                              void* d_out, int out_size, void* d_ws, size_t ws_size,
                              hipStream_t stream) {
  const float* query = (const float*)d_in[0];
  const float* key   = (const float*)d_in[1];
  const float* value = (const float*)d_in[2];
  const int*   mask  = (const int*)d_in[3];
  const float* Wq    = (const float*)d_in[4];
  const float* bq    = (const float*)d_in[5];
  float* out = (float*)d_out;

  u16t* ws = (u16t*)d_ws;
  u16t* qb = ws;
  u16t* kb = ws + (size_t)8 * 1024 * 1024;
  u16t* vb = ws + (size_t)16 * 1024 * 1024;
  u16t* wb = ws + (size_t)24 * 1024 * 1024;
  u16t* qp = ws + (size_t)25 * 1024 * 1024;

  cvt_kernel<<<2048, 256, 0, stream>>>(query, qb, (BT * NF) / 4);
  cvt_kernel<<<2048, 256, 0, stream>>>(key,   kb, (BT * NF) / 4);
  cvt_kernel<<<2048, 256, 0, stream>>>(value, vb, (BT * NF) / 4);
  cvt_kernel<<<1024, 256, 0, stream>>>(Wq,    wb, (NF * NF) / 4);

  qproj_kernel<<<dim3(BT / 128, NF / 128), 256, 0, stream>>>(qb, wb, bq, qp);
  // grid.x = (b,h): all 8 q-tiles of one (b,h) share an XCD (flat%8 = bh%8)
  attn_kernel<<<dim3(BB * NHEAD, TT / 256), 512, 0, stream>>>(qp, kb, vb, mask, out);
}

// Round 6
// 185.538 us; speedup vs baseline: 2.9723x; 2.1302x over previous
//
#include <hip/hip_runtime.h>
#include <hip/hip_bf16.h>

#define GPTR(p) ((__attribute__((address_space(1))) void*)(p))
#define LPTR(p) ((__attribute__((address_space(3))) void*)(p))

typedef __attribute__((ext_vector_type(8))) short short8;
typedef __attribute__((ext_vector_type(4))) float f32x4;
typedef __attribute__((ext_vector_type(16))) float f32x16;
typedef unsigned short u16t;
typedef unsigned int u32t;

#define NHEAD 16
#define DK 64
#define NF 1024
#define BB 4
#define TT 2048
#define BT (BB * TT) /* 8192 */

static __device__ __forceinline__ u16t f2bf(float f) {
  union { float f; unsigned u; } c; c.f = f;
  unsigned r = c.u + 0x7fffu + ((c.u >> 16) & 1u);
  return (u16t)(r >> 16);
}

__global__ void cvt_kernel(const float* __restrict__ src, u16t* __restrict__ dst, int n4) {
  int stride = gridDim.x * blockDim.x;
  for (int i = blockIdx.x * blockDim.x + threadIdx.x; i < n4; i += stride) {
    float4 f = reinterpret_cast<const float4*>(src)[i];
    ushort4 o;
    o.x = f2bf(f.x); o.y = f2bf(f.y); o.z = f2bf(f.z); o.w = f2bf(f.w);
    reinterpret_cast<ushort4*>(dst)[i] = o;
  }
}

// C = (A @ W^T + bias) * 0.125 * log2(e) ; bf16 out, fp32 acc
__launch_bounds__(256, 2)
__global__ void qproj_kernel(const u16t* __restrict__ A, const u16t* __restrict__ W,
                             const float* __restrict__ bias, u16t* __restrict__ C) {
  __shared__ u16t As[128 * 64];
  __shared__ u16t Bs[128 * 64];
  const int tid = threadIdx.x;
  const int m0 = blockIdx.x * 128;
  const int n0 = blockIdx.y * 128;
  const int w = tid >> 6, lane = tid & 63;
  const int wr = (w >> 1) * 64, wc = (w & 1) * 64;
  const int g = lane >> 4, r = lane & 15;

  f32x4 acc[4][4] = {};

  for (int kb = 0; kb < NF; kb += 64) {
    __syncthreads();
#pragma unroll
    for (int i = 0; i < 4; ++i) {
      int c = i * 256 + tid;
      int row = c >> 3, slot = c & 7;
      int gs = slot ^ (row & 7);
      __builtin_amdgcn_global_load_lds(GPTR(A + (size_t)(m0 + row) * NF + kb + gs * 8),
                                       LPTR(As + c * 8), 16, 0, 0);
    }
#pragma unroll
    for (int i = 0; i < 4; ++i) {
      int c = i * 256 + tid;
      int row = c >> 3, slot = c & 7;
      int gs = slot ^ (row & 7);
      __builtin_amdgcn_global_load_lds(GPTR(W + (size_t)(n0 + row) * NF + kb + gs * 8),
                                       LPTR(Bs + c * 8), 16, 0, 0);
    }
    __syncthreads();
#pragma unroll
    for (int kk = 0; kk < 2; ++kk) {
      short8 af[4], bfr[4];
#pragma unroll
      for (int i = 0; i < 4; ++i) {
        int row = wr + i * 16 + r;
        int slot = (4 * kk + g) ^ (row & 7);
        af[i] = *reinterpret_cast<const short8*>(As + row * 64 + slot * 8);
      }
#pragma unroll
      for (int j = 0; j < 4; ++j) {
        int row = wc + j * 16 + r;
        int slot = (4 * kk + g) ^ (row & 7);
        bfr[j] = *reinterpret_cast<const short8*>(Bs + row * 64 + slot * 8);
      }
#pragma unroll
      for (int i = 0; i < 4; ++i)
#pragma unroll
        for (int j = 0; j < 4; ++j)
          acc[i][j] = __builtin_amdgcn_mfma_f32_16x16x32_bf16(af[i], bfr[j], acc[i][j], 0, 0, 0);
    }
  }
#pragma unroll
  for (int i = 0; i < 4; ++i)
#pragma unroll
    for (int j = 0; j < 4; ++j) {
      int grow = m0 + wr + i * 16 + 4 * g;
      int gcol = n0 + wc + j * 16 + r;
      float bv = bias[gcol];
#pragma unroll
      for (int reg = 0; reg < 4; ++reg)
        C[(size_t)(grow + reg) * NF + gcol] = f2bf((acc[i][j][reg] + bv) * 0.18033688f);
    }
}

// Flash attention, swapped-QK^T: 8 waves; each block = ONE (b,h) x 512 q-rows
// (2 q-tiles of 256 against each staged K/V tile) => K/V fetch bounded by
// construction: 256 blocks x 512KB = 128MB worst case, timing-independent.
// LDS (16KB): Kl @0: row kv = 128B, 16B-slot s holds d-granule s ^ P(kv),
//   P(kv) = (kv + (kv>>3)) & 7  [conflict-free: aliasing row-quads get distinct XORs]
// Vt @8192: row d = 128B, 8B-slot s holds kv-granule Q = s ^ (d&15) ^ ((d>>4)&3)
__launch_bounds__(512, 2)
__global__ void attn_kernel(const u16t* __restrict__ Q, const u16t* __restrict__ K,
                            const u16t* __restrict__ V, const int* __restrict__ mask,
                            float* __restrict__ O) {
  __shared__ __attribute__((aligned(16))) char lds[16384];

  const int tid = threadIdx.x;
  const int lane = tid & 63;
  const int w = tid >> 6;
  const int qc = lane & 31;   // q-col for S^T / d-col for PV output
  const int hi = lane >> 5;
  const int b = blockIdx.x >> 4, h = blockIdx.x & 15;
  const size_t bbase = (size_t)b * TT * NF;
  const int hoff = h * DK;
  const int qrow0 = blockIdx.y * 512 + w * 32;   // q-tile 0; tile 1 at +256

  // Q B-frags (col=q=lane&31, k(d)=16t+8hi+e) held whole kernel, both q-tiles
  short8 qa[2][4];
#pragma unroll
  for (int qt = 0; qt < 2; ++qt)
#pragma unroll
    for (int t = 0; t < 4; ++t)
      qa[qt][t] = *reinterpret_cast<const short8*>(
          Q + bbase + (size_t)(qrow0 + 256 * qt + qc) * NF + hoff + 16 * t + 8 * hi);

  f32x16 oacc[2][2] = {};
  float lsum[2] = {0.f, 0.f};

  // K staging (DMA): chunk = tid, row = tid>>3, slot = tid&7, pre-swizzled source
  const int srow = tid >> 3, sslot = tid & 7;
  const int sgran = sslot ^ ((srow + (srow >> 3)) & 7);
  const u16t* Ksrc = K + bbase + (size_t)srow * NF + hoff + sgran * 8;

  // V staging: thread = (Qv = tid>>5, sub = (tid>>4)&1, dq = tid&15)
  const int Qv = tid >> 5, sub = (tid >> 4) & 1, dq = tid & 15;
  const u16t* Vsrc = V + bbase + (size_t)(4 * Qv + 2 * sub) * NF + hoff + 4 * dq;
  const int slotbase = Qv ^ (dq >> 2) ^ (4 * (dq & 3));
  const int wbase = 8192 + 4 * dq * 128 + (slotbase << 3) + 4 * sub;

  const int* msrc = mask + b * TT + lane;

  // read-address bases
  const int P0 = (qc + (qc >> 3)) & 7;                 // K row qc
  const int P1 = (qc + 32 + ((qc + 32) >> 3)) & 7;     // K row qc+32
  const int g0 = hi ^ (qc & 15) ^ ((qc >> 4) & 3);
  const int g1 = hi ^ (qc & 15) ^ (((qc >> 4) + 2) & 3);
  const int vb0 = 8192 + qc * 128 + (g0 << 3);         // V col d=qc
  const int vb1 = 8192 + (qc + 32) * 128 + (g1 << 3);  // V col d=qc+32

  for (int t2 = 0; t2 < TT; t2 += 64) {
    // loads at loop top (R3 schedule)
    uint2 va = *reinterpret_cast<const uint2*>(Vsrc);
    uint2 vbl = *reinterpret_cast<const uint2*>(Vsrc + NF);
    int mv = msrc[t2];
    __syncthreads();  // readers of previous tile done
    __builtin_amdgcn_global_load_lds(GPTR(Ksrc), LPTR(lds + tid * 16), 16, 0, 0);
    Ksrc += (size_t)64 * NF;
    Vsrc += (size_t)64 * NF;
    { // V writes: b64 granule (Qv, d), word sub; 2-way banked (free)
      u32t pk0 = (va.x & 0xffffu) | (vbl.x << 16);
      u32t pk1 = (va.x >> 16) | (vbl.x & 0xffff0000u);
      u32t pk2 = (va.y & 0xffffu) | (vbl.y << 16);
      u32t pk3 = (va.y >> 16) | (vbl.y & 0xffff0000u);
      *reinterpret_cast<u32t*>(lds + (wbase ^ (0 << 3)) + 0 * 128) = pk0;
      *reinterpret_cast<u32t*>(lds + (wbase ^ (1 << 3)) + 1 * 128) = pk1;
      *reinterpret_cast<u32t*>(lds + (wbase ^ (2 << 3)) + 2 * 128) = pk2;
      *reinterpret_cast<u32t*>(lds + (wbase ^ (3 << 3)) + 3 * 128) = pk3;
    }
    unsigned long long bm = __ballot(mv != 0);
    __syncthreads();  // K (vmcnt) + V (lgkm) staged

#pragma unroll
    for (int qt = 0; qt < 2; ++qt) {
      // S^T[kv][q] = K Q^T : A-frag row = kv = lane&31 (+32), k(d) = 16t+8hi+e
      f32x16 s0 = {}, s1 = {};
#pragma unroll
      for (int t = 0; t < 4; ++t) {
        short8 kf0 = *reinterpret_cast<const short8*>(
            lds + qc * 128 + (((2 * t + hi) ^ P0) << 4));
        s0 = __builtin_amdgcn_mfma_f32_32x32x16_bf16(kf0, qa[qt][t], s0, 0, 0, 0);
        short8 kf1 = *reinterpret_cast<const short8*>(
            lds + (qc + 32) * 128 + (((2 * t + hi) ^ P1) << 4));
        s1 = __builtin_amdgcn_mfma_f32_32x32x16_bf16(kf1, qa[qt][t], s1, 0, 0, 0);
      }

      // Fused mask+exp2+denominator+pack+PV, per kv-16-slice t.
      // s-reg -> kv: kv = (reg&3) + 8*(reg>>2) + 4*hi (+32 for s1).
#pragma unroll
      for (int t = 0; t < 4; ++t) {
        union { u32t u[4]; short8 s; } pa;
#pragma unroll
        for (int i = 0; i < 4; ++i) {
          const int reg = (t & 1) * 8 + 2 * i;
          const int kva = (reg & 3) + 8 * (reg >> 2) + 4 * hi + 32 * (t >> 1);
          float xa = ((bm >> kva) & 1ull) ? (t < 2 ? s0[reg] : s1[reg]) : -100.f;
          float xb = ((bm >> (kva + 1)) & 1ull) ? (t < 2 ? s0[reg + 1] : s1[reg + 1]) : -100.f;
          xa = __builtin_exp2f(xa);
          xb = __builtin_exp2f(xb);
          lsum[qt] += xa + xb;
          float2 ff; ff.x = xa; ff.y = xb;
          __hip_bfloat162 h2 = __float22bfloat162_rn(ff);
          u32t uu; __builtin_memcpy(&uu, &h2, 4);
          pa.u[i] = uu;
        }
        union { uint2 u2[2]; short8 s; } vf0, vf1;
        vf0.u2[0] = *reinterpret_cast<const uint2*>(lds + (vb0 ^ ((4 * t) << 3)));
        vf0.u2[1] = *reinterpret_cast<const uint2*>(lds + (vb0 ^ (((4 * t) ^ 2) << 3)));
        vf1.u2[0] = *reinterpret_cast<const uint2*>(lds + (vb1 ^ ((4 * t) << 3)));
        vf1.u2[1] = *reinterpret_cast<const uint2*>(lds + (vb1 ^ (((4 * t) ^ 2) << 3)));
        oacc[qt][0] = __builtin_amdgcn_mfma_f32_32x32x16_bf16(pa.s, vf0.s, oacc[qt][0], 0, 0, 0);
        oacc[qt][1] = __builtin_amdgcn_mfma_f32_32x32x16_bf16(pa.s, vf1.s, oacc[qt][1], 0, 0, 0);
      }
    }
  }

  // O[q][d]: C-layout row = (reg&3)+8*(reg>>2)+4hi, col = qc (+32)
#pragma unroll
  for (int qt = 0; qt < 2; ++qt) {
    float lall = lsum[qt] + __shfl_xor(lsum[qt], 32, 64);
    float linv = 1.0f / lall;
#pragma unroll
    for (int reg = 0; reg < 16; ++reg) {
      const int crow = (reg & 3) + 8 * (reg >> 2) + 4 * hi;
      float rl = __shfl(linv, crow, 64);
      float* orow = O + bbase + (size_t)(qrow0 + 256 * qt + crow) * NF + hoff + qc;
      orow[0] = oacc[qt][0][reg] * rl;
      orow[32] = oacc[qt][1][reg] * rl;
    }
  }
}

extern "C" void kernel_launch(void* const* d_in, const int* in_sizes, int n_in,
                              void* d_out, int out_size, void* d_ws, size_t ws_size,
                              hipStream_t stream) {
  const float* query = (const float*)d_in[0];
  const float* key   = (const float*)d_in[1];
  const float* value = (const float*)d_in[2];
  const int*   mask  = (const int*)d_in[3];
  const float* Wq    = (const float*)d_in[4];
  const float* bq    = (const float*)d_in[5];
  float* out = (float*)d_out;

  u16t* ws = (u16t*)d_ws;
  u16t* qb = ws;
  u16t* kb = ws + (size_t)8 * 1024 * 1024;
  u16t* vb = ws + (size_t)16 * 1024 * 1024;
  u16t* wb = ws + (size_t)24 * 1024 * 1024;
  u16t* qp = ws + (size_t)25 * 1024 * 1024;

  cvt_kernel<<<2048, 256, 0, stream>>>(query, qb, (BT * NF) / 4);
  cvt_kernel<<<2048, 256, 0, stream>>>(key,   kb, (BT * NF) / 4);
  cvt_kernel<<<2048, 256, 0, stream>>>(value, vb, (BT * NF) / 4);
  cvt_kernel<<<1024, 256, 0, stream>>>(Wq,    wb, (NF * NF) / 4);

  qproj_kernel<<<dim3(BT / 128, NF / 128), 256, 0, stream>>>(qb, wb, bq, qp);
  // grid: x = (b,h), y = q-pair; the 4 q-blocks of one (b,h) share an XCD (flat%8 = x%8)
  attn_kernel<<<dim3(BB * NHEAD, TT / 512), 512, 0, stream>>>(qp, kb, vb, mask, out);
}